// Round 1
// baseline (113.121 us; speedup 1.0000x reference)
//
#include <hip/hip_runtime.h>
#include <cstdint>

#define N_NODES 8192
#define DIN 128
#define DOUT 128
#define WORDS_PER_ROW (N_NODES / 32)   // 256 u32 words per adjacency row
#define MASK_BYTES (N_NODES * WORDS_PER_ROW * 4)  // 8 MB
#define EPS 1e-8f
#define GEMM_ROWS 16
#define LIST_CAP 1024

// ---------------------------------------------------------------------------
// Kernel 1: scatter-set adjacency bits (dedup via bitmask) + self loops.
// idx < E: edge (src=ei[idx], dst=ei[E+idx]); idx >= E: self loop (i,i).
// ---------------------------------------------------------------------------
__global__ void gcn_scatter(const int* __restrict__ ei, int E,
                            uint32_t* __restrict__ mask) {
    int idx = blockIdx.x * blockDim.x + threadIdx.x;
    int total = E + N_NODES;
    if (idx >= total) return;
    int src, dst;
    if (idx < E) {
        src = ei[idx];
        dst = ei[E + idx];
    } else {
        src = dst = idx - E;
    }
    atomicOr(&mask[src * WORDS_PER_ROW + (dst >> 5)], 1u << (dst & 31));
}

// ---------------------------------------------------------------------------
// Kernel 2: per-row popcount -> d_inv_sqrt. One wave (64 lanes) per row.
// ---------------------------------------------------------------------------
__global__ void gcn_degree(const uint32_t* __restrict__ mask,
                           float* __restrict__ dis) {
    int wave = (blockIdx.x * blockDim.x + threadIdx.x) >> 6;
    int lane = threadIdx.x & 63;
    if (wave >= N_NODES) return;
    const uint32_t* row = mask + (size_t)wave * WORDS_PER_ROW;
    int cnt = 0;
    // 256 words, 64 lanes -> 4 coalesced reads per lane
    for (int w = lane; w < WORDS_PER_ROW; w += 64)
        cnt += __popc(row[w]);
    // wave-64 butterfly reduce
    for (int off = 32; off > 0; off >>= 1)
        cnt += __shfl_down(cnt, off, 64);
    if (lane == 0)
        dis[wave] = rsqrtf((float)cnt + EPS);
}

// ---------------------------------------------------------------------------
// Kernel 3: z = x @ W^T   (z[n][k] = sum_d x[n][d] * W[k][d])
// 128 threads/block, thread t owns output column t for GEMM_ROWS rows.
// x tile in LDS (broadcast reads are conflict-free); W rows streamed as
// float4 from global (64 KB total, L1/L2 resident).
// ---------------------------------------------------------------------------
__global__ __launch_bounds__(128) void gcn_xw(const float* __restrict__ x,
                                              const float* __restrict__ W,
                                              float* __restrict__ z) {
    __shared__ float xlds[GEMM_ROWS][DIN];
    int t = threadIdx.x;            // 0..127 = output column
    int row0 = blockIdx.x * GEMM_ROWS;
    for (int r = 0; r < GEMM_ROWS; r++)
        xlds[r][t] = x[(size_t)(row0 + r) * DIN + t];
    __syncthreads();

    float acc[GEMM_ROWS];
#pragma unroll
    for (int r = 0; r < GEMM_ROWS; r++) acc[r] = 0.f;

    const float* wrow = W + (size_t)t * DIN;
    for (int d = 0; d < DIN; d += 4) {
        float4 wv = *(const float4*)(wrow + d);
#pragma unroll
        for (int r = 0; r < GEMM_ROWS; r++) {
            // xlds[r][d..d+3] is contiguous -> ds_read_b128, broadcast
            acc[r] += xlds[r][d + 0] * wv.x + xlds[r][d + 1] * wv.y +
                      xlds[r][d + 2] * wv.z + xlds[r][d + 3] * wv.w;
        }
    }
#pragma unroll
    for (int r = 0; r < GEMM_ROWS; r++)
        z[(size_t)(row0 + r) * DOUT + t] = acc[r];
}

// ---------------------------------------------------------------------------
// Kernel 4: out[i][t] = b[t] + dis[i] * sum_{j in row i} dis[j] * z[j][t]
// One 128-thread block per row i. Phase 1: compact set bits into LDS list.
// Phase 2: thread t accumulates column t over the neighbor list.
// ---------------------------------------------------------------------------
__global__ __launch_bounds__(128) void gcn_agg(const uint32_t* __restrict__ mask,
                                               const float* __restrict__ dis,
                                               const float* __restrict__ z,
                                               const float* __restrict__ bias,
                                               float* __restrict__ out) {
    __shared__ int list[LIST_CAP];
    __shared__ int cnt;
    int i = blockIdx.x;
    int t = threadIdx.x;  // 0..127
    if (t == 0) cnt = 0;
    __syncthreads();

    const uint32_t* row = mask + (size_t)i * WORDS_PER_ROW;
    for (int w = t; w < WORDS_PER_ROW; w += 128) {
        uint32_t m = row[w];
        while (m) {
            int bit = __ffs(m) - 1;
            m &= m - 1;
            int pos = atomicAdd(&cnt, 1);
            if (pos < LIST_CAP) list[pos] = w * 32 + bit;
        }
    }
    __syncthreads();

    int n = min(cnt, LIST_CAP);
    float acc = 0.f;
    for (int m = 0; m < n; m++) {
        int j = list[m];
        // dis[j]: same address all lanes (broadcast, cached);
        // z[j*DOUT + t]: coalesced 512B across the block
        acc += dis[j] * z[(size_t)j * DOUT + t];
    }
    out[(size_t)i * DOUT + t] = bias[t] + dis[i] * acc;
}

// ---------------------------------------------------------------------------
extern "C" void kernel_launch(void* const* d_in, const int* in_sizes, int n_in,
                              void* d_out, int out_size, void* d_ws, size_t ws_size,
                              hipStream_t stream) {
    const float* x  = (const float*)d_in[0];
    const int*   ei = (const int*)d_in[1];
    const float* W  = (const float*)d_in[2];
    const float* b  = (const float*)d_in[3];
    float* out = (float*)d_out;

    int E = in_sizes[1] / 2;

    // workspace layout: [mask 8MB][dis 32KB (pad to 64KB)][z 4MB]
    uint32_t* mask = (uint32_t*)d_ws;
    float* dis = (float*)((char*)d_ws + MASK_BYTES);
    float* z   = (float*)((char*)d_ws + MASK_BYTES + 65536);

    // zero the adjacency bitmask (ws is re-poisoned before every call)
    hipMemsetAsync(mask, 0, MASK_BYTES, stream);

    int total = E + N_NODES;
    gcn_scatter<<<(total + 255) / 256, 256, 0, stream>>>(ei, E, mask);

    // 4 waves per 256-thread block -> 2048 blocks for 8192 rows
    gcn_degree<<<N_NODES / 4, 256, 0, stream>>>(mask, dis);

    gcn_xw<<<N_NODES / GEMM_ROWS, 128, 0, stream>>>(x, W, z);

    gcn_agg<<<N_NODES, 128, 0, stream>>>(mask, dis, z, b, out);
}